// Round 13
// baseline (449.279 us; speedup 1.0000x reference)
//
#include <hip/hip_runtime.h>

typedef short bf16x8 __attribute__((ext_vector_type(8)));
typedef float f32x4 __attribute__((ext_vector_type(4)));
typedef float f32x16 __attribute__((ext_vector_type(16)));
typedef unsigned int u32x4 __attribute__((ext_vector_type(4)));
typedef unsigned short u16;
typedef unsigned int u32;

__device__ __forceinline__ u16 f2bf(float f) {
  unsigned u = __builtin_bit_cast(unsigned, f);
  u += 0x7fffu + ((u >> 16) & 1u);
  return (u16)(u >> 16);
}

__device__ __forceinline__ void async16(const void* g, void* l) {
  __builtin_amdgcn_global_load_lds(
      (const __attribute__((address_space(1))) void*)g,
      (__attribute__((address_space(3))) void*)l, 16, 0, 0);
}

// raw hw exp2 via compiler builtin (hazards handled by codegen). Args are
// <= 0 everywhere after the first rescale (s - m with s <= m).
__device__ __forceinline__ float fexp2(float x) {
#if __has_builtin(__builtin_amdgcn_exp2f)
  return __builtin_amdgcn_exp2f(x);
#else
  return exp2f(x);
#endif
}

// ---------------- convert x: f32 -> bf16, 4 elems/thread ----------------
__global__ __launch_bounds__(256) void k_cvt(const float* __restrict__ src,
                                             u16* __restrict__ dst, int n4) {
  int i = blockIdx.x * blockDim.x + threadIdx.x;
  int stride = gridDim.x * blockDim.x;
  for (; i < n4; i += stride) {
    float4 f = ((const float4*)src)[i];
    ushort4 o;
    o.x = f2bf(f.x); o.y = f2bf(f.y); o.z = f2bf(f.z); o.w = f2bf(f.w);
    ((ushort4*)dst)[i] = o;
  }
}

// ---------- transpose+convert: src[R][C] f32 -> dst[C][R] bf16 ----------
__global__ __launch_bounds__(256) void k_tcvt(const float* __restrict__ src,
                                              u16* __restrict__ dst,
                                              int R, int C) {
  __shared__ float tile[64][65];
  int c0 = blockIdx.x * 64, r0 = blockIdx.y * 64;
  int tx = threadIdx.x & 63, ty = threadIdx.x >> 6;
#pragma unroll
  for (int i = 0; i < 64; i += 4)
    tile[ty + i][tx] = src[(size_t)(r0 + ty + i) * C + c0 + tx];
  __syncthreads();
#pragma unroll
  for (int i = 0; i < 64; i += 4)
    dst[(size_t)(c0 + ty + i) * R + r0 + tx] = f2bf(tile[tx][ty + i]);
}

// ==== 256x256 GEMM: T2 swizzle + T4 counted vmcnt + 4-point stage =======
// R12 structure (2 barriers/tile). One change vs R12: stage issue spread
// to 4 points, one half-tile (2 loads) per phase: A-h0@P0, A-h1@P1,
// B-h0@P2, B-h1@P3. vmcnt(2) at P0 = exactly "tile t's 8 loads landed"
// (only A-h0(t+1)'s 2 are newer). Hazards: each half written >= 1 full
// tile after that half's last ds_read (A-halves last read P2(t-1),
// B-halves last read P1(t-1)), all separated by the tile-boundary barrier.

template <int H>
__device__ __forceinline__ void stage_half(u16* lds, const u16* gsrc, int tid) {
  const int r0 = tid >> 3, sl = tid & 7;
#pragma unroll
  for (int cc = 0; cc < 2; cc++) {
    int row = r0 + cc * 64;
    async16(gsrc + (size_t)(H * 128 + row) * 2048 + ((sl ^ (row & 7)) << 3),
            (char*)lds + ((size_t)(H * 1024 + row * 8 + sl) << 4));
  }
}

__device__ __forceinline__ void stage_tile(u16* lds, const u16* gsrc, int tid) {
  stage_half<0>(lds, gsrc, tid);
  stage_half<1>(lds, gsrc, tid);
}

template <int QM>
__device__ __forceinline__ void rd_a(bf16x8 (&dst)[4][2], const u16* base,
                                     int lo, int g) {
#pragma unroll
  for (int m2 = 0; m2 < 4; m2++)
#pragma unroll
    for (int ks = 0; ks < 2; ks++) {
      int row = QM * 64 + m2 * 16 + lo;
      dst[m2][ks] = *(const bf16x8*)((const char*)base + row * 128 +
                                     (((ks * 4 + g) ^ (row & 7)) << 4));
    }
}

template <int QN>
__device__ __forceinline__ void rd_b(bf16x8 (&dst)[2][2], const u16* base,
                                     int brow_base, int lo, int g) {
#pragma unroll
  for (int n2 = 0; n2 < 2; n2++)
#pragma unroll
    for (int ks = 0; ks < 2; ks++) {
      int row = brow_base + QN * 32 + n2 * 16 + lo;
      dst[n2][ks] = *(const bf16x8*)((const char*)base + row * 128 +
                                     (((ks * 4 + g) ^ (row & 7)) << 4));
    }
}

template <int QM, int QN>
__device__ __forceinline__ void do_mm(f32x4 (&acc)[8][4], bf16x8 (&fa)[4][2],
                                      bf16x8 (&fb)[2][2]) {
  __builtin_amdgcn_s_setprio(1);
#pragma unroll
  for (int m2 = 0; m2 < 4; m2++)
#pragma unroll
    for (int n2 = 0; n2 < 2; n2++)
#pragma unroll
      for (int ks = 0; ks < 2; ks++)
        acc[QM * 4 + m2][QN * 2 + n2] = __builtin_amdgcn_mfma_f32_16x16x32_bf16(
            fa[m2][ks], fb[n2][ks], acc[QM * 4 + m2][QN * 2 + n2], 0, 0, 0);
  __builtin_amdgcn_s_setprio(0);
}

template <int EPI, int NT>
__global__ __launch_bounds__(512, 2) void k_gemm(
    const u16* __restrict__ A, const u16* __restrict__ Bt,
    const float* __restrict__ bias,
    u16* __restrict__ qb, u16* __restrict__ kb, u16* __restrict__ vtb,
    float* __restrict__ fout) {
  __shared__ u16 aL[2][2][128 * 64];
  __shared__ u16 bL[2][2][128 * 64];
  const int tid = threadIdx.x;
  const int lane = tid & 63, w = tid >> 6;
  const int lo = lane & 15, g = lane >> 4;
  const int wm = w >> 2, wn = w & 3;
  const int brow_base = (wn & 1) * 64;
  const int nwg = NT * 32;
  const int swz = (blockIdx.x & 7) * (nwg >> 3) + (blockIdx.x >> 3);
  const int by = swz / NT, bx = swz % NT;
  const int rm0 = by * 256, cn0 = bx * 256;
  const u16* Ab = A + (size_t)rm0 * 2048;
  const u16* Bb = Bt + (size_t)cn0 * 2048;

  f32x4 acc[8][4];
#pragma unroll
  for (int i = 0; i < 8; i++)
#pragma unroll
    for (int j = 0; j < 4; j++) {
      acc[i][j][0] = 0.f; acc[i][j][1] = 0.f;
      acc[i][j][2] = 0.f; acc[i][j][3] = 0.f;
    }

  stage_tile(&aL[0][0][0], Ab, tid);
  stage_tile(&bL[0][0][0], Bb, tid);

  for (int it = 0; it < 16; ++it) {   // 32 K-tiles of 64 = full K=2048
#pragma unroll
    for (int tt = 0; tt < 2; ++tt) {
      const int tn = 2 * it + tt + 1;
      const u16* aS = &aL[tt][wm][0];
      const u16* bS = &bL[tt][wn >> 1][0];
      bf16x8 fa[4][2], fb0[2][2], fb1[2][2];
      // ---- P0: issue A-h0(t+1); vmcnt(2) == tile t fully landed ----
      if (tn < 32) {
        stage_half<0>(&aL[tt ^ 1][0][0], Ab + tn * 64, tid);
        asm volatile("s_waitcnt vmcnt(2)" ::: "memory");
      } else {
        asm volatile("s_waitcnt vmcnt(0)" ::: "memory");  // final tile
      }
      __builtin_amdgcn_s_barrier();
      rd_a<0>(fa, aS, lo, g);
      rd_b<0>(fb0, bS, brow_base, lo, g);
      asm volatile("s_waitcnt lgkmcnt(0)" ::: "memory");
      do_mm<0, 0>(acc, fa, fb0);
      // ---- P1: issue A-h1(t+1) ----
      if (tn < 32) stage_half<1>(&aL[tt ^ 1][0][0], Ab + tn * 64, tid);
      rd_b<1>(fb1, bS, brow_base, lo, g);
      asm volatile("s_waitcnt lgkmcnt(0)" ::: "memory");
      do_mm<0, 1>(acc, fa, fb1);
      // ---- P2: issue B-h0(t+1) ----
      if (tn < 32) stage_half<0>(&bL[tt ^ 1][0][0], Bb + tn * 64, tid);
      rd_a<1>(fa, aS, lo, g);
      asm volatile("s_waitcnt lgkmcnt(0)" ::: "memory");
      do_mm<1, 1>(acc, fa, fb1);
      // ---- P3: issue B-h1(t+1); regs-only MFMA ----
      if (tn < 32) stage_half<1>(&bL[tt ^ 1][0][0], Bb + tn * 64, tid);
      do_mm<1, 0>(acc, fa, fb0);
      __builtin_amdgcn_s_barrier();   // all waves done reading slot tt
    }
  }

#pragma unroll
  for (int qi = 0; qi < 8; qi++) {
    const int rowb = rm0 + wm * 128 + (qi >> 2) * 64 + (qi & 3) * 16 + g * 4;
#pragma unroll
    for (int nj = 0; nj < 4; nj++) {
      const int col = cn0 + wn * 64 + (nj >> 1) * 32 + (nj & 1) * 16 + lo;
      const float bcol = bias[col];
      const float v0 = acc[qi][nj][0] + bcol, v1 = acc[qi][nj][1] + bcol;
      const float v2 = acc[qi][nj][2] + bcol, v3 = acc[qi][nj][3] + bcol;
      if constexpr (EPI == 0) {
        const int which = col >> 11;
        const int hc = col & 2047, d = hc & 127;
        const int bh = ((rowb >> 11) << 4) | (hc >> 7);
        if (which == 2) {
          ushort4 us;
          us.x = f2bf(v0); us.y = f2bf(v1); us.z = f2bf(v2); us.w = f2bf(v3);
          *(ushort4*)(vtb + (size_t)bh * 262144 + (size_t)d * 2048 +
                      (rowb & 2047)) = us;
        } else {
          u16* dst = (which == 0) ? qb : kb;
          // q pre-scaled by D^-0.5 * log2(e): softmax runs in exp2 domain
          const float sc = (which == 0) ? 0.12751743f : 1.0f;
          size_t base = (size_t)bh * 262144 + (size_t)(rowb & 2047) * 128 + d;
          dst[base] = f2bf(v0 * sc);
          dst[base + 128] = f2bf(v1 * sc);
          dst[base + 256] = f2bf(v2 * sc);
          dst[base + 384] = f2bf(v3 * sc);
        }
      } else {
        fout[(size_t)(rowb + 0) * 2048 + col] = v0;
        fout[(size_t)(rowb + 1) * 2048 + col] = v1;
        fout[(size_t)(rowb + 2) * 2048 + col] = v2;
        fout[(size_t)(rowb + 3) * 2048 + col] = v3;
      }
    }
  }
}

// ------------- flash attention: 8 waves x 32 Q-rows, 32x32 MFMA ---------
// (unchanged from R10/R12 — measured good)
__global__ __launch_bounds__(512) void k_attn(
    const u16* __restrict__ qg, const u16* __restrict__ kg,
    const u16* __restrict__ vtg, u16* __restrict__ og) {
  __shared__ u16 kt[2][64 * 128];
  __shared__ u16 vt[2][128 * 64];
  const int bh = blockIdx.x;
  const int b = bh >> 4, h = bh & 15;
  const u16* Q = qg + (size_t)bh * 262144;
  const u16* Kp = kg + (size_t)bh * 262144;
  const u16* VT = vtg + (size_t)bh * 262144;
  const int tid = threadIdx.x;
  const int lane = tid & 63, w = tid >> 6;
  const int ql = lane & 31, hi = lane >> 5;
  const int q0 = blockIdx.y * 256 + w * 32;

  const int c0 = tid, c1 = tid + 512;
  const int kva = c0 >> 4, ksa = c0 & 15, kvb = c1 >> 4, ksb = c1 & 15;
  const size_t koff_a = (size_t)kva * 128 + (size_t)((ksa ^ (kva & 7)) * 8);
  const size_t koff_b = (size_t)kvb * 128 + (size_t)((ksb ^ (kvb & 7)) * 8);
  const int da = c0 >> 3, sva = c0 & 7, db = c1 >> 3, svb = c1 & 7;
  const size_t voff_a = (size_t)da * 2048 + (size_t)((sva ^ (da & 7)) * 8);
  const size_t voff_b = (size_t)db * 2048 + (size_t)((svb ^ (db & 7)) * 8);

  bf16x8 qf[8];
#pragma unroll
  for (int c = 0; c < 8; c++)
    qf[c] = *(const bf16x8*)(Q + (size_t)(q0 + ql) * 128 + c * 16 + hi * 8);

  f32x16 o[4];
#pragma unroll
  for (int nd = 0; nd < 4; nd++)
#pragma unroll
    for (int r = 0; r < 16; r++) o[nd][r] = 0.f;
  float m = -1e30f, l = 0.f;   // l = per-half partial (combined in epilogue)

  {
    async16(Kp + koff_a, &kt[0][c0 * 8]);
    async16(Kp + koff_b, &kt[0][c1 * 8]);
    async16(VT + voff_a, &vt[0][c0 * 8]);
    async16(VT + voff_b, &vt[0][c1 * 8]);
  }
  int cur = 0;
  for (int kv0 = 0; kv0 < 2048; kv0 += 64) {
    __syncthreads();
    if (kv0 + 64 < 2048) {
      const u16* kbp = Kp + (size_t)(kv0 + 64) * 128;
      const u16* vbp = VT + (kv0 + 64);
      int nx = cur ^ 1;
      async16(kbp + koff_a, &kt[nx][c0 * 8]);
      async16(kbp + koff_b, &kt[nx][c1 * 8]);
      async16(vbp + voff_a, &vt[nx][c0 * 8]);
      async16(vbp + voff_b, &vt[nx][c1 * 8]);
    }
    const char* ktb = (const char*)&kt[cur][0];
    const char* vtb = (const char*)&vt[cur][0];

    // ---- S^T = K · Q^T ----
    f32x16 sacc[2];
#pragma unroll
    for (int s2 = 0; s2 < 2; s2++)
#pragma unroll
      for (int r = 0; r < 16; r++) sacc[s2][r] = 0.f;
    __builtin_amdgcn_s_setprio(1);
#pragma unroll
    for (int c = 0; c < 8; c++)
#pragma unroll
      for (int s2 = 0; s2 < 2; s2++) {
        int kv = s2 * 32 + ql;
        int phys = kv * 256 + ((c * 32 + hi * 16) ^ ((kv & 7) << 4));
        bf16x8 kf = *(const bf16x8*)(ktb + phys);
        sacc[s2] = __builtin_amdgcn_mfma_f32_32x32x16_bf16(kf, qf[c], sacc[s2], 0, 0, 0);
      }
    __builtin_amdgcn_s_setprio(0);

    // ---- online softmax (exp2 domain; per-lane q) ----
    float tm = sacc[0][0];
#pragma unroll
    for (int r = 1; r < 16; r++) tm = fmaxf(tm, sacc[0][r]);
#pragma unroll
    for (int r = 0; r < 16; r++) tm = fmaxf(tm, sacc[1][r]);
    tm = fmaxf(tm, __shfl_xor(tm, 32));
    if (!__all(tm <= m)) {   // defer-max THR=0 (corr==1 when skipped)
      float mnew = fmaxf(m, tm);
      float corr = fexp2(m - mnew);
      l *= corr;
#pragma unroll
      for (int nd = 0; nd < 4; nd++)
#pragma unroll
        for (int r = 0; r < 16; r++) o[nd][r] *= corr;
      m = mnew;
    }
#pragma unroll
    for (int s2 = 0; s2 < 2; s2++)
#pragma unroll
      for (int r = 0; r < 16; r++) {
        float p = fexp2(sacc[s2][r] - m);
        sacc[s2][r] = p;
        l += p;
      }

    // ---- P -> bf16 frags in-register (cvt_pk + permlane32_swap) ----
    bf16x8 pf[4];
#pragma unroll
    for (int s2 = 0; s2 < 2; s2++) {
      u32 pk[8];
#pragma unroll
      for (int i = 0; i < 8; i++) {
        u32 t;
        asm("v_cvt_pk_bf16_f32 %0, %1, %2"
            : "=v"(t) : "v"(sacc[s2][2 * i]), "v"(sacc[s2][2 * i + 1]));
        pk[i] = t;
      }
#pragma unroll
      for (int ksl = 0; ksl < 2; ksl++) {
        u32 a0 = pk[4 * ksl + 0], b0 = pk[4 * ksl + 2];
        u32 a1 = pk[4 * ksl + 1], b1 = pk[4 * ksl + 3];
        asm("v_permlane32_swap_b32 %0, %1" : "+v"(a0), "+v"(b0));
        asm("v_permlane32_swap_b32 %0, %1" : "+v"(a1), "+v"(b1));
        u32x4 fr = {a0, a1, b0, b1};
        pf[s2 * 2 + ksl] = __builtin_bit_cast(bf16x8, fr);
      }
    }

    // ---- O^T += V^T · P^T ----
    __builtin_amdgcn_s_setprio(1);
#pragma unroll
    for (int nd = 0; nd < 4; nd++)
#pragma unroll
      for (int ks = 0; ks < 4; ks++) {
        int d = nd * 32 + ql;
        int phys = d * 128 + ((ks * 32 + hi * 16) ^ ((d & 7) << 4));
        bf16x8 vf = *(const bf16x8*)(vtb + phys);
        o[nd] = __builtin_amdgcn_mfma_f32_32x32x16_bf16(vf, pf[ks], o[nd], 0, 0, 0);
      }
    __builtin_amdgcn_s_setprio(0);
    cur ^= 1;
  }

  // combine the two half-range partial sums once (same basis m)
  float lt = l + __shfl_xor(l, 32);
  float inv = 1.0f / lt;
  size_t rowbase = ((size_t)(b * 2048 + q0 + ql)) * 2048 + h * 128 + hi * 4;
#pragma unroll
  for (int nd = 0; nd < 4; nd++)
#pragma unroll
    for (int j2 = 0; j2 < 4; j2++) {
      ushort4 us;
      us.x = f2bf(o[nd][4 * j2 + 0] * inv);
      us.y = f2bf(o[nd][4 * j2 + 1] * inv);
      us.z = f2bf(o[nd][4 * j2 + 2] * inv);
      us.w = f2bf(o[nd][4 * j2 + 3] * inv);
      *(ushort4*)(og + rowbase + nd * 32 + j2 * 8) = us;
    }
}

extern "C" void kernel_launch(void* const* d_in, const int* in_sizes, int n_in,
                              void* d_out, int out_size, void* d_ws, size_t ws_size,
                              hipStream_t stream) {
  const float* x      = (const float*)d_in[0];   // [4,2048,2048]
  const float* w_qkv  = (const float*)d_in[1];   // [2048,6144]
  const float* b_qkv  = (const float*)d_in[2];   // [6144]
  const float* w_proj = (const float*)d_in[3];   // [2048,2048]
  const float* b_proj = (const float*)d_in[4];   // [2048]
  float* out = (float*)d_out;

  char* p = (char*)d_ws;
  u16* xb     = (u16*)p; p += (size_t)8192 * 2048 * 2;   // x bf16; later reused as att
  u16* wqkvT  = (u16*)p; p += (size_t)6144 * 2048 * 2;
  u16* wprojT = (u16*)p; p += (size_t)2048 * 2048 * 2;
  u16* qb     = (u16*)p; p += (size_t)64 * 2048 * 128 * 2;
  u16* kb     = (u16*)p; p += (size_t)64 * 2048 * 128 * 2;
  u16* vtb    = (u16*)p; p += (size_t)64 * 2048 * 128 * 2;  // total 160 MiB

  k_cvt<<<2048, 256, 0, stream>>>(x, xb, (8192 * 2048) / 4);
  k_tcvt<<<dim3(6144 / 64, 2048 / 64), 256, 0, stream>>>(w_qkv, wqkvT, 2048, 6144);
  k_tcvt<<<dim3(2048 / 64, 2048 / 64), 256, 0, stream>>>(w_proj, wprojT, 2048, 2048);
  k_gemm<0, 24><<<768, 512, 0, stream>>>(xb, wqkvT, b_qkv, qb, kb, vtb, nullptr);
  k_attn<<<dim3(64, 8), 512, 0, stream>>>(qb, kb, vtb, xb);
  k_gemm<1, 8><<<256, 512, 0, stream>>>(xb, wprojT, b_proj, nullptr, nullptr, nullptr, out);
}

// Round 14
// 445.081 us; speedup vs baseline: 1.0094x; 1.0094x over previous
//
#include <hip/hip_runtime.h>

typedef short bf16x8 __attribute__((ext_vector_type(8)));
typedef float f32x4 __attribute__((ext_vector_type(4)));
typedef float f32x16 __attribute__((ext_vector_type(16)));
typedef unsigned int u32x4 __attribute__((ext_vector_type(4)));
typedef unsigned short u16;
typedef unsigned int u32;

__device__ __forceinline__ u16 f2bf(float f) {
  unsigned u = __builtin_bit_cast(unsigned, f);
  u += 0x7fffu + ((u >> 16) & 1u);
  return (u16)(u >> 16);
}

__device__ __forceinline__ void async16(const void* g, void* l) {
  __builtin_amdgcn_global_load_lds(
      (const __attribute__((address_space(1))) void*)g,
      (__attribute__((address_space(3))) void*)l, 16, 0, 0);
}

// raw hw exp2 via compiler builtin (hazards handled by codegen). Args are
// <= 0 everywhere after the first rescale (s - m with s <= m).
__device__ __forceinline__ float fexp2(float x) {
#if __has_builtin(__builtin_amdgcn_exp2f)
  return __builtin_amdgcn_exp2f(x);
#else
  return exp2f(x);
#endif
}

__device__ __forceinline__ float max3f(float a, float b, float c) {
  return fmaxf(fmaxf(a, b), c);  // clang fuses to v_max3_f32
}

// ---------------- convert x: f32 -> bf16, 4 elems/thread ----------------
__global__ __launch_bounds__(256) void k_cvt(const float* __restrict__ src,
                                             u16* __restrict__ dst, int n4) {
  int i = blockIdx.x * blockDim.x + threadIdx.x;
  int stride = gridDim.x * blockDim.x;
  for (; i < n4; i += stride) {
    float4 f = ((const float4*)src)[i];
    ushort4 o;
    o.x = f2bf(f.x); o.y = f2bf(f.y); o.z = f2bf(f.z); o.w = f2bf(f.w);
    ((ushort4*)dst)[i] = o;
  }
}

// ---------- transpose+convert: src[R][C] f32 -> dst[C][R] bf16 ----------
__global__ __launch_bounds__(256) void k_tcvt(const float* __restrict__ src,
                                              u16* __restrict__ dst,
                                              int R, int C) {
  __shared__ float tile[64][65];
  int c0 = blockIdx.x * 64, r0 = blockIdx.y * 64;
  int tx = threadIdx.x & 63, ty = threadIdx.x >> 6;
#pragma unroll
  for (int i = 0; i < 64; i += 4)
    tile[ty + i][tx] = src[(size_t)(r0 + ty + i) * C + c0 + tx];
  __syncthreads();
#pragma unroll
  for (int i = 0; i < 64; i += 4)
    dst[(size_t)(c0 + ty + i) * R + r0 + tx] = f2bf(tile[tx][ty + i]);
}

// ==== 256x256 GEMM: T2 swizzle + T4 counted vmcnt + split stage issue ====
// R12 exact form (best measured: 200.5 us, MfmaUtil 44.4%). A(t+1) issued
// at P0 then vmcnt(4) ("tile t fully landed", 4 newer A-loads in flight);
// B(t+1) at P2. 2 barriers/tile (R11's per-phase barriers regressed;
// R13's 4-point spread was neutral — both reverted).

__device__ __forceinline__ void stage_tile(u16* lds, const u16* gsrc, int tid) {
  const int r0 = tid >> 3, sl = tid & 7;
#pragma unroll
  for (int h = 0; h < 2; h++)
#pragma unroll
    for (int cc = 0; cc < 2; cc++) {
      int row = r0 + cc * 64;
      async16(gsrc + (size_t)(h * 128 + row) * 2048 + ((sl ^ (row & 7)) << 3),
              (char*)lds + ((size_t)(h * 1024 + row * 8 + sl) << 4));
    }
}

template <int QM>
__device__ __forceinline__ void rd_a(bf16x8 (&dst)[4][2], const u16* base,
                                     int lo, int g) {
#pragma unroll
  for (int m2 = 0; m2 < 4; m2++)
#pragma unroll
    for (int ks = 0; ks < 2; ks++) {
      int row = QM * 64 + m2 * 16 + lo;
      dst[m2][ks] = *(const bf16x8*)((const char*)base + row * 128 +
                                     (((ks * 4 + g) ^ (row & 7)) << 4));
    }
}

template <int QN>
__device__ __forceinline__ void rd_b(bf16x8 (&dst)[2][2], const u16* base,
                                     int brow_base, int lo, int g) {
#pragma unroll
  for (int n2 = 0; n2 < 2; n2++)
#pragma unroll
    for (int ks = 0; ks < 2; ks++) {
      int row = brow_base + QN * 32 + n2 * 16 + lo;
      dst[n2][ks] = *(const bf16x8*)((const char*)base + row * 128 +
                                     (((ks * 4 + g) ^ (row & 7)) << 4));
    }
}

template <int QM, int QN>
__device__ __forceinline__ void do_mm(f32x4 (&acc)[8][4], bf16x8 (&fa)[4][2],
                                      bf16x8 (&fb)[2][2]) {
  __builtin_amdgcn_s_setprio(1);
#pragma unroll
  for (int m2 = 0; m2 < 4; m2++)
#pragma unroll
    for (int n2 = 0; n2 < 2; n2++)
#pragma unroll
      for (int ks = 0; ks < 2; ks++)
        acc[QM * 4 + m2][QN * 2 + n2] = __builtin_amdgcn_mfma_f32_16x16x32_bf16(
            fa[m2][ks], fb[n2][ks], acc[QM * 4 + m2][QN * 2 + n2], 0, 0, 0);
  __builtin_amdgcn_s_setprio(0);
}

template <int EPI, int NT>
__global__ __launch_bounds__(512, 2) void k_gemm(
    const u16* __restrict__ A, const u16* __restrict__ Bt,
    const float* __restrict__ bias,
    u16* __restrict__ qb, u16* __restrict__ kb, u16* __restrict__ vtb,
    float* __restrict__ fout) {
  __shared__ u16 aL[2][2][128 * 64];
  __shared__ u16 bL[2][2][128 * 64];
  const int tid = threadIdx.x;
  const int lane = tid & 63, w = tid >> 6;
  const int lo = lane & 15, g = lane >> 4;
  const int wm = w >> 2, wn = w & 3;
  const int brow_base = (wn & 1) * 64;
  const int nwg = NT * 32;
  const int swz = (blockIdx.x & 7) * (nwg >> 3) + (blockIdx.x >> 3);
  const int by = swz / NT, bx = swz % NT;
  const int rm0 = by * 256, cn0 = bx * 256;
  const u16* Ab = A + (size_t)rm0 * 2048;
  const u16* Bb = Bt + (size_t)cn0 * 2048;

  f32x4 acc[8][4];
#pragma unroll
  for (int i = 0; i < 8; i++)
#pragma unroll
    for (int j = 0; j < 4; j++) {
      acc[i][j][0] = 0.f; acc[i][j][1] = 0.f;
      acc[i][j][2] = 0.f; acc[i][j][3] = 0.f;
    }

  stage_tile(&aL[0][0][0], Ab, tid);
  stage_tile(&bL[0][0][0], Bb, tid);

  for (int it = 0; it < 16; ++it) {   // 32 K-tiles of 64 = full K=2048
#pragma unroll
    for (int tt = 0; tt < 2; ++tt) {
      const int tn = 2 * it + tt + 1;
      const u16* aS = &aL[tt][wm][0];
      const u16* bS = &bL[tt][wn >> 1][0];
      bf16x8 fa[4][2], fb0[2][2], fb1[2][2];
      // ---- P0: issue A(t+1), counted wait on tile t (4 newer in flight)
      if (tn < 32) {
        stage_tile(&aL[tt ^ 1][0][0], Ab + tn * 64, tid);
        asm volatile("s_waitcnt vmcnt(4)" ::: "memory");  // tile t landed
      } else {
        asm volatile("s_waitcnt vmcnt(0)" ::: "memory");  // final tile
      }
      __builtin_amdgcn_s_barrier();
      rd_a<0>(fa, aS, lo, g);
      rd_b<0>(fb0, bS, brow_base, lo, g);
      asm volatile("s_waitcnt lgkmcnt(0)" ::: "memory");
      do_mm<0, 0>(acc, fa, fb0);
      // ---- P1 ----
      rd_b<1>(fb1, bS, brow_base, lo, g);
      asm volatile("s_waitcnt lgkmcnt(0)" ::: "memory");
      do_mm<0, 1>(acc, fa, fb1);
      // ---- P2: issue B(t+1) (slot^1 B-frags dead since t-1/P1) ----
      if (tn < 32) stage_tile(&bL[tt ^ 1][0][0], Bb + tn * 64, tid);
      rd_a<1>(fa, aS, lo, g);
      asm volatile("s_waitcnt lgkmcnt(0)" ::: "memory");
      do_mm<1, 1>(acc, fa, fb1);
      // ---- P3 (regs only) ----
      do_mm<1, 0>(acc, fa, fb0);
      __builtin_amdgcn_s_barrier();   // all waves done reading slot tt
    }
  }

#pragma unroll
  for (int qi = 0; qi < 8; qi++) {
    const int rowb = rm0 + wm * 128 + (qi >> 2) * 64 + (qi & 3) * 16 + g * 4;
#pragma unroll
    for (int nj = 0; nj < 4; nj++) {
      const int col = cn0 + wn * 64 + (nj >> 1) * 32 + (nj & 1) * 16 + lo;
      const float bcol = bias[col];
      const float v0 = acc[qi][nj][0] + bcol, v1 = acc[qi][nj][1] + bcol;
      const float v2 = acc[qi][nj][2] + bcol, v3 = acc[qi][nj][3] + bcol;
      if constexpr (EPI == 0) {
        const int which = col >> 11;
        const int hc = col & 2047, d = hc & 127;
        const int bh = ((rowb >> 11) << 4) | (hc >> 7);
        if (which == 2) {
          ushort4 us;
          us.x = f2bf(v0); us.y = f2bf(v1); us.z = f2bf(v2); us.w = f2bf(v3);
          *(ushort4*)(vtb + (size_t)bh * 262144 + (size_t)d * 2048 +
                      (rowb & 2047)) = us;
        } else {
          u16* dst = (which == 0) ? qb : kb;
          // q pre-scaled by D^-0.5 * log2(e): softmax runs in exp2 domain
          const float sc = (which == 0) ? 0.12751743f : 1.0f;
          size_t base = (size_t)bh * 262144 + (size_t)(rowb & 2047) * 128 + d;
          dst[base] = f2bf(v0 * sc);
          dst[base + 128] = f2bf(v1 * sc);
          dst[base + 256] = f2bf(v2 * sc);
          dst[base + 384] = f2bf(v3 * sc);
        }
      } else {
        fout[(size_t)(rowb + 0) * 2048 + col] = v0;
        fout[(size_t)(rowb + 1) * 2048 + col] = v1;
        fout[(size_t)(rowb + 2) * 2048 + col] = v2;
        fout[(size_t)(rowb + 3) * 2048 + col] = v3;
      }
    }
  }
}

// ------------- flash attention: 8 waves x 32 Q-rows, 32x32 MFMA ---------
// R12 structure. Two pure-VALU reorders this round (no lane-semantics
// changes): (1) max3 tree for the row-max (31 serial fmax -> 16-op tree,
// depth ~4); (2) 4-way partial l-sum (32 serial adds -> 4x8 + combine).
__global__ __launch_bounds__(512) void k_attn(
    const u16* __restrict__ qg, const u16* __restrict__ kg,
    const u16* __restrict__ vtg, u16* __restrict__ og) {
  __shared__ u16 kt[2][64 * 128];
  __shared__ u16 vt[2][128 * 64];
  const int bh = blockIdx.x;
  const int b = bh >> 4, h = bh & 15;
  const u16* Q = qg + (size_t)bh * 262144;
  const u16* Kp = kg + (size_t)bh * 262144;
  const u16* VT = vtg + (size_t)bh * 262144;
  const int tid = threadIdx.x;
  const int lane = tid & 63, w = tid >> 6;
  const int ql = lane & 31, hi = lane >> 5;
  const int q0 = blockIdx.y * 256 + w * 32;

  const int c0 = tid, c1 = tid + 512;
  const int kva = c0 >> 4, ksa = c0 & 15, kvb = c1 >> 4, ksb = c1 & 15;
  const size_t koff_a = (size_t)kva * 128 + (size_t)((ksa ^ (kva & 7)) * 8);
  const size_t koff_b = (size_t)kvb * 128 + (size_t)((ksb ^ (kvb & 7)) * 8);
  const int da = c0 >> 3, sva = c0 & 7, db = c1 >> 3, svb = c1 & 7;
  const size_t voff_a = (size_t)da * 2048 + (size_t)((sva ^ (da & 7)) * 8);
  const size_t voff_b = (size_t)db * 2048 + (size_t)((svb ^ (db & 7)) * 8);

  bf16x8 qf[8];
#pragma unroll
  for (int c = 0; c < 8; c++)
    qf[c] = *(const bf16x8*)(Q + (size_t)(q0 + ql) * 128 + c * 16 + hi * 8);

  f32x16 o[4];
#pragma unroll
  for (int nd = 0; nd < 4; nd++)
#pragma unroll
    for (int r = 0; r < 16; r++) o[nd][r] = 0.f;
  float m = -1e30f, l = 0.f;   // l = per-half partial (combined in epilogue)

  {
    async16(Kp + koff_a, &kt[0][c0 * 8]);
    async16(Kp + koff_b, &kt[0][c1 * 8]);
    async16(VT + voff_a, &vt[0][c0 * 8]);
    async16(VT + voff_b, &vt[0][c1 * 8]);
  }
  int cur = 0;
  for (int kv0 = 0; kv0 < 2048; kv0 += 64) {
    __syncthreads();
    if (kv0 + 64 < 2048) {
      const u16* kbp = Kp + (size_t)(kv0 + 64) * 128;
      const u16* vbp = VT + (kv0 + 64);
      int nx = cur ^ 1;
      async16(kbp + koff_a, &kt[nx][c0 * 8]);
      async16(kbp + koff_b, &kt[nx][c1 * 8]);
      async16(vbp + voff_a, &vt[nx][c0 * 8]);
      async16(vbp + voff_b, &vt[nx][c1 * 8]);
    }
    const char* ktb = (const char*)&kt[cur][0];
    const char* vtb = (const char*)&vt[cur][0];

    // ---- S^T = K · Q^T ----
    f32x16 sacc[2];
#pragma unroll
    for (int s2 = 0; s2 < 2; s2++)
#pragma unroll
      for (int r = 0; r < 16; r++) sacc[s2][r] = 0.f;
    __builtin_amdgcn_s_setprio(1);
#pragma unroll
    for (int c = 0; c < 8; c++)
#pragma unroll
      for (int s2 = 0; s2 < 2; s2++) {
        int kv = s2 * 32 + ql;
        int phys = kv * 256 + ((c * 32 + hi * 16) ^ ((kv & 7) << 4));
        bf16x8 kf = *(const bf16x8*)(ktb + phys);
        sacc[s2] = __builtin_amdgcn_mfma_f32_32x32x16_bf16(kf, qf[c], sacc[s2], 0, 0, 0);
      }
    __builtin_amdgcn_s_setprio(0);

    // ---- online softmax (exp2 domain; per-lane q; max3 tree) ----
    float t0 = max3f(sacc[0][0], sacc[0][1], sacc[0][2]);
    float t1 = max3f(sacc[0][3], sacc[0][4], sacc[0][5]);
    float t2 = max3f(sacc[0][6], sacc[0][7], sacc[0][8]);
    float t3 = max3f(sacc[0][9], sacc[0][10], sacc[0][11]);
    float t4 = max3f(sacc[0][12], sacc[0][13], sacc[0][14]);
    float t5 = max3f(sacc[0][15], sacc[1][0], sacc[1][1]);
    float t6 = max3f(sacc[1][2], sacc[1][3], sacc[1][4]);
    float t7 = max3f(sacc[1][5], sacc[1][6], sacc[1][7]);
    float t8 = max3f(sacc[1][8], sacc[1][9], sacc[1][10]);
    float t9 = max3f(sacc[1][11], sacc[1][12], sacc[1][13]);
    float ta = fmaxf(sacc[1][14], sacc[1][15]);
    t0 = max3f(t0, t1, t2); t3 = max3f(t3, t4, t5);
    t6 = max3f(t6, t7, t8); t9 = max3f(t9, ta, t0);
    float tm = max3f(t3, t6, t9);
    tm = fmaxf(tm, __shfl_xor(tm, 32));
    if (!__all(tm <= m)) {   // defer-max THR=0 (corr==1 when skipped)
      float mnew = fmaxf(m, tm);
      float corr = fexp2(m - mnew);
      l *= corr;
#pragma unroll
      for (int nd = 0; nd < 4; nd++)
#pragma unroll
        for (int r = 0; r < 16; r++) o[nd][r] *= corr;
      m = mnew;
    }
    // exp2 + 4-way partial sums (ILP; reassociation only)
    float ps0 = 0.f, ps1 = 0.f, ps2 = 0.f, ps3 = 0.f;
#pragma unroll
    for (int s2 = 0; s2 < 2; s2++)
#pragma unroll
      for (int r = 0; r < 16; r++) {
        float p = fexp2(sacc[s2][r] - m);
        sacc[s2][r] = p;
        if (s2 == 0 && r < 8) ps0 += p;
        else if (s2 == 0) ps1 += p;
        else if (r < 8) ps2 += p;
        else ps3 += p;
      }
    l += (ps0 + ps1) + (ps2 + ps3);

    // ---- P -> bf16 frags in-register (cvt_pk + permlane32_swap) ----
    bf16x8 pf[4];
#pragma unroll
    for (int s2 = 0; s2 < 2; s2++) {
      u32 pk[8];
#pragma unroll
      for (int i = 0; i < 8; i++) {
        u32 t;
        asm("v_cvt_pk_bf16_f32 %0, %1, %2"
            : "=v"(t) : "v"(sacc[s2][2 * i]), "v"(sacc[s2][2 * i + 1]));
        pk[i] = t;
      }
#pragma unroll
      for (int ksl = 0; ksl < 2; ksl++) {
        u32 a0 = pk[4 * ksl + 0], b0 = pk[4 * ksl + 2];
        u32 a1 = pk[4 * ksl + 1], b1 = pk[4 * ksl + 3];
        asm("v_permlane32_swap_b32 %0, %1" : "+v"(a0), "+v"(b0));
        asm("v_permlane32_swap_b32 %0, %1" : "+v"(a1), "+v"(b1));
        u32x4 fr = {a0, a1, b0, b1};
        pf[s2 * 2 + ksl] = __builtin_bit_cast(bf16x8, fr);
      }
    }

    // ---- O^T += V^T · P^T ----
    __builtin_amdgcn_s_setprio(1);
#pragma unroll
    for (int nd = 0; nd < 4; nd++)
#pragma unroll
      for (int ks = 0; ks < 4; ks++) {
        int d = nd * 32 + ql;
        int phys = d * 128 + ((ks * 32 + hi * 16) ^ ((d & 7) << 4));
        bf16x8 vf = *(const bf16x8*)(vtb + phys);
        o[nd] = __builtin_amdgcn_mfma_f32_32x32x16_bf16(vf, pf[ks], o[nd], 0, 0, 0);
      }
    __builtin_amdgcn_s_setprio(0);
    cur ^= 1;
  }

  // combine the two half-range partial sums once (same basis m)
  float lt = l + __shfl_xor(l, 32);
  float inv = 1.0f / lt;
  size_t rowbase = ((size_t)(b * 2048 + q0 + ql)) * 2048 + h * 128 + hi * 4;
#pragma unroll
  for (int nd = 0; nd < 4; nd++)
#pragma unroll
    for (int j2 = 0; j2 < 4; j2++) {
      ushort4 us;
      us.x = f2bf(o[nd][4 * j2 + 0] * inv);
      us.y = f2bf(o[nd][4 * j2 + 1] * inv);
      us.z = f2bf(o[nd][4 * j2 + 2] * inv);
      us.w = f2bf(o[nd][4 * j2 + 3] * inv);
      *(ushort4*)(og + rowbase + nd * 32 + j2 * 8) = us;
    }
}

extern "C" void kernel_launch(void* const* d_in, const int* in_sizes, int n_in,
                              void* d_out, int out_size, void* d_ws, size_t ws_size,
                              hipStream_t stream) {
  const float* x      = (const float*)d_in[0];   // [4,2048,2048]
  const float* w_qkv  = (const float*)d_in[1];   // [2048,6144]
  const float* b_qkv  = (const float*)d_in[2];   // [6144]
  const float* w_proj = (const float*)d_in[3];   // [2048,2048]
  const float* b_proj = (const float*)d_in[4];   // [2048]
  float* out = (float*)d_out;

  char* p = (char*)d_ws;
  u16* xb     = (u16*)p; p += (size_t)8192 * 2048 * 2;   // x bf16; later reused as att
  u16* wqkvT  = (u16*)p; p += (size_t)6144 * 2048 * 2;
  u16* wprojT = (u16*)p; p += (size_t)2048 * 2048 * 2;
  u16* qb     = (u16*)p; p += (size_t)64 * 2048 * 128 * 2;
  u16* kb     = (u16*)p; p += (size_t)64 * 2048 * 128 * 2;
  u16* vtb    = (u16*)p; p += (size_t)64 * 2048 * 128 * 2;  // total 160 MiB

  k_cvt<<<2048, 256, 0, stream>>>(x, xb, (8192 * 2048) / 4);
  k_tcvt<<<dim3(6144 / 64, 2048 / 64), 256, 0, stream>>>(w_qkv, wqkvT, 2048, 6144);
  k_tcvt<<<dim3(2048 / 64, 2048 / 64), 256, 0, stream>>>(w_proj, wprojT, 2048, 2048);
  k_gemm<0, 24><<<768, 512, 0, stream>>>(xb, wqkvT, b_qkv, qb, kb, vtb, nullptr);
  k_attn<<<dim3(64, 8), 512, 0, stream>>>(qb, kb, vtb, xb);
  k_gemm<1, 8><<<256, 512, 0, stream>>>(xb, wprojT, b_proj, nullptr, nullptr, nullptr, out);
}